// Round 18
// baseline (219.456 us; speedup 1.0000x reference)
//
#include <hip/hip_runtime.h>
#include <math.h>

#define NN 8192
#define DD 128
#define KK 128
#define EE 262144
#define BCAP 128

typedef _Float16 f16;
typedef __attribute__((ext_vector_type(8))) _Float16 f16x8;
typedef __attribute__((ext_vector_type(4))) _Float16 f16x4;
typedef __attribute__((ext_vector_type(4))) float f32x4;

// ---------------------------------------------------------------- activation
__device__ __forceinline__ float mishf(float v){
  float e  = __expf(v);
  float t2 = e * (e + 2.f);
  float r  = v * (t2 / (t2 + 2.f));
  return (v > 30.f) ? v : r;
}

// fp8 e4m3 (OCP) manual encode of non-negative f
__device__ __forceinline__ unsigned char enc_fp8(float f){
  unsigned u = __float_as_uint(f) + 0x00080000u;      // round mantissa to 3 bits
  int e8 = (int)(u >> 23) - 120;                      // bias: 127-7
  if (e8 >= 1) return (unsigned char)(((unsigned)e8 << 3) | ((u >> 20) & 7u));
  return (unsigned char)(f * 512.f + 0.5f);           // subnormal: m * 2^-9
}
__device__ __forceinline__ float dec_fp8(unsigned b){
  unsigned e = (b >> 3) & 0xFu;
  return e ? __uint_as_float(((e + 120u) << 23) | ((b & 7u) << 20))
           : (float)(b & 7u) * 0.001953125f;          // 2^-9
}

// ---------------------------------------------------------------- fused prep: cast + single-pass bucket CSR + wprep
// grid (774, 2): [0,512) cast, [512,768) bucket-fill, [768,774) wprep
__global__ __launch_bounds__(256) void prep_kernel(
    const float* __restrict__ x0, const float* __restrict__ x1,
    f16* __restrict__ f0, f16* __restrict__ f1,
    const int* __restrict__ eA, const int* __restrict__ eB,
    int* cntA, int* cntB,
    int* __restrict__ bkA, int* __restrict__ bkB,
    const float* w0, const float* w1, const float* w2, const float* w3,
    const float* w4, const float* w5, const float* w6, const float* w7,
    const float* w8, const float* w9, const float* w10, const float* w11,
    f16* WT){
  int g = blockIdx.y;
  int bx = blockIdx.x;
  int t = threadIdx.x;
  if (bx < 512){
    const float* x = g ? x1 : x0;
    f16* f = g ? f1 : f0;
    int idx = bx * 256 + t;
    const float4* p = (const float4*)&x[idx * 8];
    float4 a = p[0], b = p[1];
    f16x8 o;
    o[0] = (f16)a.x; o[1] = (f16)a.y; o[2] = (f16)a.z; o[3] = (f16)a.w;
    o[4] = (f16)b.x; o[5] = (f16)b.y; o[6] = (f16)b.z; o[7] = (f16)b.w;
    *(f16x8*)&f[idx * 8] = o;
  } else if (bx < 768){
    const int* e  = g ? eB : eA;
    int* cnt = g ? cntB : cntA;
    int* bk  = g ? bkB  : bkA;
    const int* src = e;
    const int* dst = e + EE;
    for (int i = (bx - 512) * 256 + t; i < EE; i += 65536){
      int d = dst[i], s = src[i];
      int pos = atomicAdd(&cnt[d], 1);
      bk[d * BCAP + pos] = s;
    }
  } else {
    const float* Ws[12] = {w0,w1,w2,w3,w4,w5,w6,w7,w8,w9,w10,w11};
    int widx = (bx - 768) * 2 + g;
    const float* W = Ws[widx];
    f16* O = WT + (size_t)widx * 16384;
    int n = t >> 1, k0 = (t & 1) * 64;
#pragma unroll
    for (int seg = 0; seg < 8; ++seg){
      f16x8 o;
#pragma unroll
      for (int q = 0; q < 8; ++q)
        o[q] = (f16)W[(k0 + seg * 8 + q) * 128 + n];
      *(f16x8*)&O[n * 128 + k0 + seg * 8] = o;
    }
  }
}

// ---------------------------------------------------------------- fused aggregate + GEMM (bucket CSR)
template<int DUAL, int ACT, int FUSEADD>
__global__ __launch_bounds__(256) void aggemm(
    const int* __restrict__ cntA, const int* __restrict__ cntB,
    const int* __restrict__ bkA, const int* __restrict__ bkB,
    const f16* __restrict__ FA, const f16* __restrict__ FBg,
    const f16* __restrict__ BA, const f16* __restrict__ BBm,
    const f16* __restrict__ WaT0, const f16* __restrict__ WaT1,
    const f16* __restrict__ WbT0, const f16* __restrict__ WbT1,
    const float* __restrict__ bi0, const float* __restrict__ bi1,
    const f16* __restrict__ ADD0, const f16* __restrict__ ADD1,
    f16* __restrict__ O0, f16* __restrict__ O1){
  int g = blockIdx.y;
  const int* cnt = g ? cntB : cntA;
  const int* bk  = g ? bkB  : bkA;
  const f16* F  = g ? FBg : FA;
  const f16* Bm = g ? BBm : BA;
  const f16* WaT = g ? WaT1 : WaT0;
  const f16* WbT = g ? WbT1 : WbT0;
  const float* bi = g ? bi1 : bi0;
  const f16* ADD = g ? ADD1 : ADD0;
  f16* O = g ? O1 : O0;

  __shared__ f16 AT[32][136];
  int t = threadIdx.x;
  int rowBase = blockIdx.x * 32;

  {
    int r = t >> 3;
    int lane = t & 7;
    int c0 = lane * 16;
    int node = rowBase + r;
    int nc = cnt[node];
    const int* lst = bk + node * BCAP;
    float a[16];
#pragma unroll
    for (int k = 0; k < 16; ++k) a[k] = 0.f;
    int j = 0;
    for (; j + 4 <= nc; j += 4){
      int s0 = lst[j], s1 = lst[j + 1], s2 = lst[j + 2], s3 = lst[j + 3];
      f16x8 u0 = *(const f16x8*)&F[s0 * DD + c0];
      f16x8 u1 = *(const f16x8*)&F[s0 * DD + c0 + 8];
      f16x8 v0 = *(const f16x8*)&F[s1 * DD + c0];
      f16x8 v1 = *(const f16x8*)&F[s1 * DD + c0 + 8];
      f16x8 w0 = *(const f16x8*)&F[s2 * DD + c0];
      f16x8 w1 = *(const f16x8*)&F[s2 * DD + c0 + 8];
      f16x8 y0 = *(const f16x8*)&F[s3 * DD + c0];
      f16x8 y1 = *(const f16x8*)&F[s3 * DD + c0 + 8];
#pragma unroll
      for (int k = 0; k < 8; ++k){
        a[k]     += ((float)u0[k] + (float)v0[k]) + ((float)w0[k] + (float)y0[k]);
        a[k + 8] += ((float)u1[k] + (float)v1[k]) + ((float)w1[k] + (float)y1[k]);
      }
    }
    for (; j < nc; ++j){
      int s = lst[j];
      f16x8 u0 = *(const f16x8*)&F[s * DD + c0];
      f16x8 u1 = *(const f16x8*)&F[s * DD + c0 + 8];
#pragma unroll
      for (int k = 0; k < 8; ++k){ a[k] += (float)u0[k]; a[k + 8] += (float)u1[k]; }
    }
    float inv = 1.f / fmaxf((float)nc, 1.f);
    f16x8 o0, o1;
#pragma unroll
    for (int k = 0; k < 8; ++k){ o0[k] = (f16)(a[k] * inv); o1[k] = (f16)(a[k + 8] * inv); }
    *(f16x8*)&AT[r][c0]     = o0;
    *(f16x8*)&AT[r][c0 + 8] = o1;
  }
  __syncthreads();

  int wave = t >> 6, l = t & 63;
  int lrow = l & 15;
  int lk = (l >> 4) * 8;
  int rt = wave >> 1, nh = wave & 1;
  int rowW = rowBase + rt * 16;

  f32x4 acc[4];
#pragma unroll
  for (int q = 0; q < 4; ++q) acc[q] = (f32x4){0.f, 0.f, 0.f, 0.f};

#pragma unroll
  for (int kc = 0; kc < 4; ++kc){
    int kb = kc * 32 + lk;
    f16x8 a0 = *(const f16x8*)&AT[rt * 16 + lrow][kb];
#pragma unroll
    for (int q = 0; q < 4; ++q){
      int nt = nh * 4 + q;
      f16x8 bw = *(const f16x8*)&WaT[(nt * 16 + lrow) * 128 + kb];
      acc[q] = __builtin_amdgcn_mfma_f32_16x16x32_f16(a0, bw, acc[q], 0, 0, 0);
    }
    if (DUAL){
      f16x8 c0v = *(const f16x8*)&Bm[(rowW + lrow) * 128 + kb];
#pragma unroll
      for (int q = 0; q < 4; ++q){
        int nt = nh * 4 + q;
        f16x8 bw = *(const f16x8*)&WbT[(nt * 16 + lrow) * 128 + kb];
        acc[q] = __builtin_amdgcn_mfma_f32_16x16x32_f16(c0v, bw, acc[q], 0, 0, 0);
      }
    }
  }

  int col16 = l & 15;
  int rgrp = (l >> 4) * 4;
#pragma unroll
  for (int r = 0; r < 4; ++r){
    int row = rowW + rgrp + r;
    float v[4];
#pragma unroll
    for (int q = 0; q < 4; ++q) v[q] = acc[q][r] + bi[(nh * 4 + q) * 16 + col16];
    if (ACT == 1){
#pragma unroll
      for (int q = 0; q < 4; ++q) v[q] = mishf(v[q]);
    }
    if (FUSEADD){
#pragma unroll
      for (int q = 0; q < 4; ++q)
        v[q] += (float)ADD[row * 128 + (nh * 4 + q) * 16 + col16];
    }
#pragma unroll
    for (int q = 0; q < 4; ++q)
      O[row * 128 + (nh * 4 + q) * 16 + col16] = (f16)v[q];
  }
}

// ---------------------------------------------------------------- fused MLP: t = H@W1+b1 (LDS), s = softmax(t@W2+b2)
__global__ __launch_bounds__(128) void mlp_kernel(
    const f16* __restrict__ H0, const f16* __restrict__ H1,
    const f16* __restrict__ W1T, const f16* __restrict__ W2T,
    const float* __restrict__ b1, const float* __restrict__ b2,
    f16* __restrict__ O0, f16* __restrict__ O1,
    unsigned char* __restrict__ S80, unsigned char* __restrict__ S81){
  int g = blockIdx.y;
  const f16* A = g ? H1 : H0;
  f16* O = g ? O1 : O0;
  unsigned char* S8 = g ? S81 : S80;

  __shared__ f16 T[32][136];
  int t = threadIdx.x;
  int wave = t >> 6, l = t & 63;
  int lrow = l & 15;
  int lk = (l >> 4) * 8;
  int rowBase = blockIdx.x * 32 + wave * 16;
  int col16 = l & 15;
  int rgrp = (l >> 4) * 4;

  f32x4 acc[8];
#pragma unroll
  for (int nt = 0; nt < 8; ++nt) acc[nt] = (f32x4){0.f, 0.f, 0.f, 0.f};
#pragma unroll
  for (int kc = 0; kc < 4; ++kc){
    int kb = kc * 32 + lk;
    f16x8 a0 = *(const f16x8*)&A[(rowBase + lrow) * 128 + kb];
#pragma unroll
    for (int nt = 0; nt < 8; ++nt){
      f16x8 bw = *(const f16x8*)&W1T[(nt * 16 + lrow) * 128 + kb];
      acc[nt] = __builtin_amdgcn_mfma_f32_16x16x32_f16(a0, bw, acc[nt], 0, 0, 0);
    }
  }
#pragma unroll
  for (int r = 0; r < 4; ++r)
#pragma unroll
    for (int nt = 0; nt < 8; ++nt)
      T[wave * 16 + rgrp + r][nt * 16 + col16] = (f16)(acc[nt][r] + b1[nt * 16 + col16]);
  __syncthreads();

  f32x4 acc2[8];
#pragma unroll
  for (int nt = 0; nt < 8; ++nt) acc2[nt] = (f32x4){0.f, 0.f, 0.f, 0.f};
#pragma unroll
  for (int kc = 0; kc < 4; ++kc){
    int kb = kc * 32 + lk;
    f16x8 a0 = *(const f16x8*)&T[wave * 16 + lrow][kb];
#pragma unroll
    for (int nt = 0; nt < 8; ++nt){
      f16x8 bw = *(const f16x8*)&W2T[(nt * 16 + lrow) * 128 + kb];
      acc2[nt] = __builtin_amdgcn_mfma_f32_16x16x32_f16(a0, bw, acc2[nt], 0, 0, 0);
    }
  }

  float bv[8];
#pragma unroll
  for (int nt = 0; nt < 8; ++nt) bv[nt] = b2[nt * 16 + col16];
#pragma unroll
  for (int r = 0; r < 4; ++r){
    int row = rowBase + rgrp + r;
    float v[8];
#pragma unroll
    for (int nt = 0; nt < 8; ++nt) v[nt] = acc2[nt][r] + bv[nt];
    float m = v[0];
#pragma unroll
    for (int nt = 1; nt < 8; ++nt) m = fmaxf(m, v[nt]);
    for (int msk = 1; msk < 16; msk <<= 1) m = fmaxf(m, __shfl_xor(m, msk));
    float sum = 0.f;
#pragma unroll
    for (int nt = 0; nt < 8; ++nt){ v[nt] = __expf(v[nt] - m); sum += v[nt]; }
    for (int msk = 1; msk < 16; msk <<= 1) sum += __shfl_xor(sum, msk);
    float inv = 1.f / sum;
#pragma unroll
    for (int nt = 0; nt < 8; ++nt) v[nt] *= inv;
#pragma unroll
    for (int nt = 0; nt < 8; ++nt){
      O[row * 128 + nt * 16 + col16] = (f16)v[nt];
      S8[row * 128 + nt * 16 + col16] = enc_fp8(v[nt] * 64.f);
    }
  }
}

// ---------------------------------------------------------------- transpose [8192][128]->[128][8192] (+colsum for z=0)
__global__ __launch_bounds__(256) void transpose_kernel(
    const f16* __restrict__ in0A, const f16* __restrict__ in1A,   // z=0 src (S)
    const f16* __restrict__ in0B, const f16* __restrict__ in1B,   // z=1 src (Hf)
    f16* __restrict__ o0A, f16* __restrict__ o1A,
    f16* __restrict__ o0B, f16* __restrict__ o1B,
    float* col0, float* col1){
  int g = blockIdx.y, z = blockIdx.z;
  const f16* in = z ? (g ? in1B : in0B) : (g ? in1A : in0A);
  f16* outp     = z ? (g ? o1B  : o0B)  : (g ? o1A  : o0A);
  __shared__ f16 T[32][136];
  int t = threadIdx.x;
  int i0 = blockIdx.x * 32;
#pragma unroll
  for (int j = 0; j < 2; ++j){
    int idx = t + j * 256;
    int row = idx >> 4, c8 = (idx & 15) * 8;
    f16x8 v = *(const f16x8*)&in[(i0 + row) * 128 + c8];
#pragma unroll
    for (int q = 0; q < 8; ++q) T[row][c8 + q] = v[q];
  }
  __syncthreads();
  int k = t >> 1, seg = (t & 1) * 16;
  f16x8 oA, oB;
#pragma unroll
  for (int q = 0; q < 8; ++q){ oA[q] = T[seg + q][k]; oB[q] = T[seg + 8 + q][k]; }
  *(f16x8*)&outp[(size_t)k * NN + i0 + seg]     = oA;
  *(f16x8*)&outp[(size_t)k * NN + i0 + seg + 8] = oB;

  if (z == 0){
    float* col = g ? col1 : col0;
    int kk = t & 127, half = t >> 7;
    float cs = 0.f;
#pragma unroll
    for (int i = 0; i < 16; ++i)
      cs += (float)T[half * 16 + i][kk];
    atomicAdd(&col[kk], cs);
  }
}

// ---------------------------------------------------------------- merged pool (MFMA split-K) + trace (fp8, half-split) + ca
// grid (1056, 2): bx<32 -> pool; bx>=32 -> trace: nodeGroup=(bx-32)>>1, half=(bx-32)&1
#define PK_NSPLIT 16
__global__ __launch_bounds__(256) void pooltrace_kernel(
    const f16* __restrict__ ST0, const f16* __restrict__ ST1,
    const f16* __restrict__ HT0, const f16* __restrict__ HT1,
    float* __restrict__ PART,
    const int* __restrict__ cntA, const int* __restrict__ cntB,
    const int* __restrict__ bkA, const int* __restrict__ bkB,
    const f16* __restrict__ SA, const f16* __restrict__ SBp,
    const unsigned char* __restrict__ S8A, const unsigned char* __restrict__ S8B,
    float* tr0, float* tr1, float* ca0, float* ca1){
  int g = blockIdx.y;
  int bx = blockIdx.x;
  int t = threadIdx.x;
  if (bx < 32){
    int z = bx >> 4, split = bx & 15;
    const f16* A = g ? ST1 : ST0;
    const f16* B = z ? A : (g ? HT1 : HT0);
    float* OUT = PART + ((size_t)(z * 2 + g) * PK_NSPLIT + split) * 16384;

    int wave = t >> 6, l = t & 63;
    int lrow = l & 15;
    int lk = (l >> 4) * 8;
    int krow = wave * 32;
    int i0 = split * (NN / PK_NSPLIT);

    f32x4 acc[2][8];
#pragma unroll
    for (int rt = 0; rt < 2; ++rt)
#pragma unroll
      for (int nt = 0; nt < 8; ++nt)
        acc[rt][nt] = (f32x4){0.f, 0.f, 0.f, 0.f};

#pragma unroll 2
    for (int c = 0; c < NN / PK_NSPLIT; c += 32){
      int ib = i0 + c + lk;
      f16x8 a0 = *(const f16x8*)&A[(size_t)(krow + lrow) * NN + ib];
      f16x8 a1 = *(const f16x8*)&A[(size_t)(krow + 16 + lrow) * NN + ib];
#pragma unroll
      for (int nt = 0; nt < 8; ++nt){
        f16x8 bf = *(const f16x8*)&B[(size_t)(nt * 16 + lrow) * NN + ib];
        acc[0][nt] = __builtin_amdgcn_mfma_f32_16x16x32_f16(a0, bf, acc[0][nt], 0, 0, 0);
        acc[1][nt] = __builtin_amdgcn_mfma_f32_16x16x32_f16(a1, bf, acc[1][nt], 0, 0, 0);
      }
    }

    int col = l & 15;
    int rbase = (l >> 4) * 4;
#pragma unroll
    for (int rt = 0; rt < 2; ++rt)
#pragma unroll
      for (int nt = 0; nt < 8; ++nt)
#pragma unroll
        for (int r = 0; r < 4; ++r)
          OUT[(krow + rt * 16 + rbase + r) * 128 + nt * 16 + col] = acc[rt][nt][r];
  } else {
    const int* cnt = g ? cntB : cntA;
    const int* bk  = g ? bkB  : bkA;
    const f16* S = g ? SBp : SA;
    const unsigned char* S8 = g ? S8B : S8A;
    float* tr = g ? tr1 : tr0;
    float* ca = g ? ca1 : ca0;
    int grp = t >> 4, lane = t & 15;       // 16 nodes/group, 16 lanes x 8 elems
    int bb = bx - 32;
    int node = (bb >> 1) * 16 + grp;
    int half = bb & 1;
    int nc = cnt[node];
    int j0 = half ? (nc >> 1) : 0;
    int j1 = half ? nc : (nc >> 1);
    const int* lst = bk + node * BCAP;
    f16x8 w = *(const f16x8*)&S[node * DD + lane * 8];   // exact fp16 dst row
    float o[8], cak[8];
#pragma unroll
    for (int k = 0; k < 8; ++k){ o[k] = (float)w[k]; cak[k] = 0.f; }
    float acc = 0.f;
    int j = j0;
    for (; j + 4 <= j1; j += 4){
      int s0 = lst[j], s1 = lst[j + 1], s2 = lst[j + 2], s3 = lst[j + 3];
      uint2 q0 = *(const uint2*)&S8[s0 * DD + lane * 8];
      uint2 q1 = *(const uint2*)&S8[s1 * DD + lane * 8];
      uint2 q2 = *(const uint2*)&S8[s2 * DD + lane * 8];
      uint2 q3 = *(const uint2*)&S8[s3 * DD + lane * 8];
#pragma unroll
      for (int k = 0; k < 4; ++k){
        float lo = (dec_fp8((q0.x >> (8*k)) & 0xFF) + dec_fp8((q1.x >> (8*k)) & 0xFF))
                 + (dec_fp8((q2.x >> (8*k)) & 0xFF) + dec_fp8((q3.x >> (8*k)) & 0xFF));
        float hi = (dec_fp8((q0.y >> (8*k)) & 0xFF) + dec_fp8((q1.y >> (8*k)) & 0xFF))
                 + (dec_fp8((q2.y >> (8*k)) & 0xFF) + dec_fp8((q3.y >> (8*k)) & 0xFF));
        acc += o[k] * lo + o[k + 4] * hi;
        cak[k] += lo; cak[k + 4] += hi;
      }
    }
    for (; j < j1; ++j){
      int s = lst[j];
      uint2 q = *(const uint2*)&S8[s * DD + lane * 8];
#pragma unroll
      for (int k = 0; k < 4; ++k){
        float lo = dec_fp8((q.x >> (8*k)) & 0xFF);
        float hi = dec_fp8((q.y >> (8*k)) & 0xFF);
        acc += o[k] * lo + o[k + 4] * hi;
        cak[k] += lo; cak[k + 4] += hi;
      }
    }
    for (int m = 1; m < 16; m <<= 1) acc += __shfl_xor(acc, m);
    __shared__ float part[16];
    __shared__ float pca[16][128];
    if (lane == 0) part[grp] = acc;
#pragma unroll
    for (int k = 0; k < 8; ++k) pca[grp][lane * 8 + k] = cak[k];
    __syncthreads();
    if (t == 0){
      float s = 0.f;
#pragma unroll
      for (int i = 0; i < 16; ++i) s += part[i];
      atomicAdd(tr, s * 0.015625f);   // /64 (fp8 stored S*64)
    }
    if (t < 128){
      float s = 0.f;
#pragma unroll
      for (int i = 0; i < 16; ++i) s += pca[i][t];
      atomicAdd(&ca[t], s * 0.015625f);
    }
  }
}

// ---------------------------------------------------------------- reduce partials; z=0 -> selu->out, z=1 -> F2/trss scalars
__global__ __launch_bounds__(256) void reduce_kernel(
    const float* __restrict__ PART,
    float* __restrict__ out, float* F2acc, float* trssacc){
  int g = blockIdx.y, z = blockIdx.z;
  int t = threadIdx.x;
  int idx = blockIdx.x * 256 + t;
  const float* base = PART + (size_t)(z * 2 + g) * PK_NSPLIT * 16384 + idx;
  float s = 0.f;
#pragma unroll
  for (int sp = 0; sp < PK_NSPLIT; ++sp) s += base[sp * 16384];
  if (z == 0){
    const float scale = 1.0507009873554805f, alpha = 1.6732632423543772f;
    float r = (s > 0.f) ? scale * s : scale * alpha * expm1f(s);
    out[g * 16384 + idx] = r;
  } else {
    float f2p = s * s;
    float trp = (idx % 129 == 0) ? s : 0.f;
    __shared__ float r1[256], r2[256];
    r1[t] = f2p; r2[t] = trp; __syncthreads();
    for (int o = 128; o > 0; o >>= 1){
      if (t < o){ r1[t] += r1[t + o]; r2[t] += r2[t + o]; }
      __syncthreads();
    }
    if (t == 0){
      atomicAdd(&F2acc[g], r1[0]);
      atomicAdd(&trssacc[g], r2[0]);
    }
  }
}

// ---------------------------------------------------------------- finalize: both graphs, direct store
__global__ __launch_bounds__(128) void finalize_kernel(
    const float* col0, const float* col1, const float* ca0, const float* ca1,
    const float* tr0, const float* tr1, const float* F2acc, const float* trssacc,
    float* loss_out){
  __shared__ float r1[128], r2[128];
  __shared__ float total_s;
  int t = threadIdx.x;
  if (t == 0) total_s = 0.f;
  for (int g = 0; g < 2; ++g){
    const float* col = g ? col1 : col0;
    const float* ca  = g ? ca1  : ca0;
    const float* tr  = g ? tr1  : tr0;
    __syncthreads();
    r1[t] = ca[t] * ca[t];
    r2[t] = col[t] * col[t];
    __syncthreads();
    for (int o = 64; o > 0; o >>= 1){
      if (t < o){ r1[t] += r1[t + o]; r2[t] += r2[t + o]; }
      __syncthreads();
    }
    if (t == 0){
      float ca2 = r1[0], cs2 = r2[0];
      float F = sqrtf(F2acc[g]);
      float ortho = sqrtf(fmaxf(2.f - 2.f * trssacc[g] / (F * sqrtf((float)KK)), 0.f));
      float m2 = (float)EE;               // 2m
      float spectral = -(tr[0] - ca2 / m2) / m2;
      float cluster = sqrtf(cs2) / (float)NN * sqrtf((float)KK) - 1.f;
      total_s += spectral + ortho + cluster;
    }
  }
  __syncthreads();
  if (t == 0) loss_out[0] = total_s;
}

// ---------------------------------------------------------------- launch
extern "C" void kernel_launch(void* const* d_in, const int* in_sizes, int n_in,
                              void* d_out, int out_size, void* d_ws, size_t ws_size,
                              hipStream_t stream){
  const float* x1 = (const float*)d_in[0];
  const float* x2 = (const float*)d_in[1];
  const int*   e1 = (const int*)d_in[2];
  const int*   e2 = (const int*)d_in[3];
  const float* c1_Wl = (const float*)d_in[4];
  const float* c1_bl = (const float*)d_in[5];
  const float* c1_Wr = (const float*)d_in[6];
  const float* c2_Wl = (const float*)d_in[7];
  const float* c2_bl = (const float*)d_in[8];
  const float* c2_Wr = (const float*)d_in[9];
  const float* co_Wl = (const float*)d_in[10];
  const float* co_bl = (const float*)d_in[11];
  const float* co_Wr = (const float*)d_in[12];
  const float* c3_Wl = (const float*)d_in[13];
  const float* c3_bl = (const float*)d_in[14];
  const float* c3_Wr = (const float*)d_in[15];
  const float* c4_Wl = (const float*)d_in[16];
  const float* c4_bl = (const float*)d_in[17];
  const float* c4_Wr = (const float*)d_in[18];
  const float* m_W1 = (const float*)d_in[19];
  const float* m_b1 = (const float*)d_in[20];
  const float* m_W2 = (const float*)d_in[21];
  const float* m_b2 = (const float*)d_in[22];
  float* out = (float*)d_out;

  char* w = (char*)d_ws;
  auto alloc = [&](size_t bytes) -> char* {
    char* p = w;
    w += (bytes + 255) / 256 * 256;
    return p;
  };
  // zero region: counts + small accumulators (contiguous)
  int* cnt0 = (int*)alloc(NN * 4);
  int* cnt1 = (int*)alloc(NN * 4);
  float* col0 = (float*)alloc(128 * 4);
  float* ca0  = (float*)alloc(128 * 4);
  float* tr0  = (float*)alloc(256);
  float* col1 = (float*)alloc(128 * 4);
  float* ca1  = (float*)alloc(128 * 4);
  float* tr1  = (float*)alloc(256);
  float* F2acc   = (float*)alloc(2 * 4);
  float* trssacc = (float*)alloc(2 * 4);
  size_t zero_len = (size_t)(w - (char*)cnt0);
  // buckets (only slots < cnt read; no zeroing)
  int* bk0 = (int*)alloc((size_t)NN * BCAP * 4);
  int* bk1 = (int*)alloc((size_t)NN * BCAP * 4);
  // split-K partials: [z][g][split][16384]
  float* PART = (float*)alloc((size_t)4 * PK_NSPLIT * 16384 * 4);
  // transposed fp16 weights (12 x 128x128)
  f16* WT = (f16*)alloc(12 * 16384 * sizeof(f16));
  // fp8 S copies for trace
  unsigned char* S8_0 = (unsigned char*)alloc((size_t)NN * DD);
  unsigned char* S8_1 = (unsigned char*)alloc((size_t)NN * DD);
  // fp16 feature buffers, 2 MB each
  f16* F1_0 = (f16*)alloc((size_t)NN * DD * 2);
  f16* F3_0 = (f16*)alloc((size_t)NN * DD * 2);
  f16* F4_0 = (f16*)alloc((size_t)NN * DD * 2);
  f16* F5_0 = (f16*)alloc((size_t)NN * DD * 2);
  f16* F1_1 = (f16*)alloc((size_t)NN * DD * 2);
  f16* F3_1 = (f16*)alloc((size_t)NN * DD * 2);
  f16* F4_1 = (f16*)alloc((size_t)NN * DD * 2);
  f16* F5_1 = (f16*)alloc((size_t)NN * DD * 2);

  hipMemsetAsync(cnt0, 0, zero_len, stream);

  // fused prep: cast x->fp16 + single-pass bucket CSR + weight transpose
  prep_kernel<<<dim3(774, 2), 256, 0, stream>>>(
      x1, x2, F1_0, F1_1, e1, e2, cnt0, cnt1, bk0, bk1,
      c1_Wl, c1_Wr, c2_Wl, c2_Wr, co_Wl, co_Wr,
      c3_Wl, c3_Wr, c4_Wl, c4_Wr, m_W1, m_W2, WT);

  f16* W_c1l = WT;            f16* W_c1r = WT + 16384;
  f16* W_c2l = WT + 2*16384;  f16* W_c2r = WT + 3*16384;
  f16* W_col = WT + 4*16384;  f16* W_cor = WT + 5*16384;
  f16* W_c3l = WT + 6*16384;  f16* W_c3r = WT + 7*16384;
  f16* W_c4l = WT + 8*16384;  f16* W_c4r = WT + 9*16384;
  f16* W_m1  = WT + 10*16384; f16* W_m2  = WT + 11*16384;

  // sage1: h = mish(mean(x)@Wl + x@Wr + bl) -> F3   (fused agg+gemm)
  aggemm<1, 1, 0><<<dim3(256, 2), 256, 0, stream>>>(cnt0, cnt1, bk0, bk1,
      F1_0, F1_1, F1_0, F1_1, W_c1l, W_c2l, W_c1r, W_c2r, c1_bl, c2_bl,
      nullptr, nullptr, F3_0, F3_1);

  // sage2 (shared co weights) + residual: z = h + mish(sage(h)) -> F1
  aggemm<1, 1, 1><<<dim3(256, 2), 256, 0, stream>>>(cnt0, cnt1, bk0, bk1,
      F3_0, F3_1, F3_0, F3_1, W_col, W_col, W_cor, W_cor, co_bl, co_bl,
      F3_0, F3_1, F1_0, F1_1);

  // sage3: h_final = mish(sage(z)) -> F4
  aggemm<1, 1, 0><<<dim3(256, 2), 256, 0, stream>>>(cnt0, cnt1, bk0, bk1,
      F1_0, F1_1, F1_0, F1_1, W_c3l, W_c4l, W_c3r, W_c4r, c3_bl, c4_bl,
      nullptr, nullptr, F4_0, F4_1);

  // dmon MLP fused: s = softmax((h@W1+b1)@W2+b2) -> F5 (+ fp8 copy -> S8)
  mlp_kernel<<<dim3(256, 2), 128, 0, stream>>>(F4_0, F4_1, W_m1, W_m2,
      m_b1, m_b2, F5_0, F5_1, S8_0, S8_1);

  // transpose S -> ST (F1), Hf -> HT (F3); colsum fused on z=0
  transpose_kernel<<<dim3(256, 2, 2), 256, 0, stream>>>(
      F5_0, F5_1, F4_0, F4_1, F1_0, F1_1, F3_0, F3_1, col0, col1);

  // merged: pooled/ss split-K MFMA + trace gather (fp8, half-split) + ca
  pooltrace_kernel<<<dim3(1056, 2), 256, 0, stream>>>(
      F1_0, F1_1, F3_0, F3_1, PART,
      cnt0, cnt1, bk0, bk1, F5_0, F5_1, S8_0, S8_1, tr0, tr1, ca0, ca1);
  reduce_kernel<<<dim3(64, 2, 2), 256, 0, stream>>>(PART, out, F2acc, trssacc);

  finalize_kernel<<<1, 128, 0, stream>>>(col0, col1, ca0, ca1, tr0, tr1,
      F2acc, trssacc, out + 32768);
}

// Round 19
// 199.495 us; speedup vs baseline: 1.1001x; 1.1001x over previous
//
#include <hip/hip_runtime.h>
#include <math.h>

#define NN 8192
#define DD 128
#define KK 128
#define EE 262144
#define BCAP 128

typedef _Float16 f16;
typedef __attribute__((ext_vector_type(8))) _Float16 f16x8;
typedef __attribute__((ext_vector_type(4))) _Float16 f16x4;
typedef __attribute__((ext_vector_type(4))) float f32x4;

// ---------------------------------------------------------------- activation
__device__ __forceinline__ float mishf(float v){
  float e  = __expf(v);
  float t2 = e * (e + 2.f);
  float r  = v * (t2 / (t2 + 2.f));
  return (v > 30.f) ? v : r;
}

// fp8 e4m3 (OCP) manual encode of non-negative f
__device__ __forceinline__ unsigned char enc_fp8(float f){
  unsigned u = __float_as_uint(f) + 0x00080000u;      // round mantissa to 3 bits
  int e8 = (int)(u >> 23) - 120;                      // bias: 127-7
  if (e8 >= 1) return (unsigned char)(((unsigned)e8 << 3) | ((u >> 20) & 7u));
  return (unsigned char)(f * 512.f + 0.5f);           // subnormal: m * 2^-9
}
__device__ __forceinline__ float dec_fp8(unsigned b){
  unsigned e = (b >> 3) & 0xFu;
  return e ? __uint_as_float(((e + 120u) << 23) | ((b & 7u) << 20))
           : (float)(b & 7u) * 0.001953125f;          // 2^-9
}

// ---------------------------------------------------------------- fused prep: cast + single-pass bucket CSR + wprep
// grid (774, 2): [0,512) cast, [512,768) bucket-fill, [768,774) wprep
__global__ __launch_bounds__(256) void prep_kernel(
    const float* __restrict__ x0, const float* __restrict__ x1,
    f16* __restrict__ f0, f16* __restrict__ f1,
    const int* __restrict__ eA, const int* __restrict__ eB,
    int* cntA, int* cntB,
    int* __restrict__ bkA, int* __restrict__ bkB,
    const float* w0, const float* w1, const float* w2, const float* w3,
    const float* w4, const float* w5, const float* w6, const float* w7,
    const float* w8, const float* w9, const float* w10, const float* w11,
    f16* WT){
  int g = blockIdx.y;
  int bx = blockIdx.x;
  int t = threadIdx.x;
  if (bx < 512){
    const float* x = g ? x1 : x0;
    f16* f = g ? f1 : f0;
    int idx = bx * 256 + t;
    const float4* p = (const float4*)&x[idx * 8];
    float4 a = p[0], b = p[1];
    f16x8 o;
    o[0] = (f16)a.x; o[1] = (f16)a.y; o[2] = (f16)a.z; o[3] = (f16)a.w;
    o[4] = (f16)b.x; o[5] = (f16)b.y; o[6] = (f16)b.z; o[7] = (f16)b.w;
    *(f16x8*)&f[idx * 8] = o;
  } else if (bx < 768){
    const int* e  = g ? eB : eA;
    int* cnt = g ? cntB : cntA;
    int* bk  = g ? bkB  : bkA;
    const int* src = e;
    const int* dst = e + EE;
    for (int i = (bx - 512) * 256 + t; i < EE; i += 65536){
      int d = dst[i], s = src[i];
      int pos = atomicAdd(&cnt[d], 1);
      bk[d * BCAP + pos] = s;
    }
  } else {
    const float* Ws[12] = {w0,w1,w2,w3,w4,w5,w6,w7,w8,w9,w10,w11};
    int widx = (bx - 768) * 2 + g;
    const float* W = Ws[widx];
    f16* O = WT + (size_t)widx * 16384;
    int n = t >> 1, k0 = (t & 1) * 64;
#pragma unroll
    for (int seg = 0; seg < 8; ++seg){
      f16x8 o;
#pragma unroll
      for (int q = 0; q < 8; ++q)
        o[q] = (f16)W[(k0 + seg * 8 + q) * 128 + n];
      *(f16x8*)&O[n * 128 + k0 + seg * 8] = o;
    }
  }
}

// ---------------------------------------------------------------- fused aggregate + GEMM (bucket CSR)
template<int DUAL, int ACT, int FUSEADD>
__global__ __launch_bounds__(256) void aggemm(
    const int* __restrict__ cntA, const int* __restrict__ cntB,
    const int* __restrict__ bkA, const int* __restrict__ bkB,
    const f16* __restrict__ FA, const f16* __restrict__ FBg,
    const f16* __restrict__ BA, const f16* __restrict__ BBm,
    const f16* __restrict__ WaT0, const f16* __restrict__ WaT1,
    const f16* __restrict__ WbT0, const f16* __restrict__ WbT1,
    const float* __restrict__ bi0, const float* __restrict__ bi1,
    const f16* __restrict__ ADD0, const f16* __restrict__ ADD1,
    f16* __restrict__ O0, f16* __restrict__ O1){
  int g = blockIdx.y;
  const int* cnt = g ? cntB : cntA;
  const int* bk  = g ? bkB  : bkA;
  const f16* F  = g ? FBg : FA;
  const f16* Bm = g ? BBm : BA;
  const f16* WaT = g ? WaT1 : WaT0;
  const f16* WbT = g ? WbT1 : WbT0;
  const float* bi = g ? bi1 : bi0;
  const f16* ADD = g ? ADD1 : ADD0;
  f16* O = g ? O1 : O0;

  __shared__ f16 AT[32][136];
  int t = threadIdx.x;
  int rowBase = blockIdx.x * 32;

  {
    int r = t >> 3;
    int lane = t & 7;
    int c0 = lane * 16;
    int node = rowBase + r;
    int nc = cnt[node];
    const int* lst = bk + node * BCAP;
    float a[16];
#pragma unroll
    for (int k = 0; k < 16; ++k) a[k] = 0.f;
    int j = 0;
    for (; j + 4 <= nc; j += 4){
      int s0 = lst[j], s1 = lst[j + 1], s2 = lst[j + 2], s3 = lst[j + 3];
      f16x8 u0 = *(const f16x8*)&F[s0 * DD + c0];
      f16x8 u1 = *(const f16x8*)&F[s0 * DD + c0 + 8];
      f16x8 v0 = *(const f16x8*)&F[s1 * DD + c0];
      f16x8 v1 = *(const f16x8*)&F[s1 * DD + c0 + 8];
      f16x8 w0 = *(const f16x8*)&F[s2 * DD + c0];
      f16x8 w1 = *(const f16x8*)&F[s2 * DD + c0 + 8];
      f16x8 y0 = *(const f16x8*)&F[s3 * DD + c0];
      f16x8 y1 = *(const f16x8*)&F[s3 * DD + c0 + 8];
#pragma unroll
      for (int k = 0; k < 8; ++k){
        a[k]     += ((float)u0[k] + (float)v0[k]) + ((float)w0[k] + (float)y0[k]);
        a[k + 8] += ((float)u1[k] + (float)v1[k]) + ((float)w1[k] + (float)y1[k]);
      }
    }
    for (; j < nc; ++j){
      int s = lst[j];
      f16x8 u0 = *(const f16x8*)&F[s * DD + c0];
      f16x8 u1 = *(const f16x8*)&F[s * DD + c0 + 8];
#pragma unroll
      for (int k = 0; k < 8; ++k){ a[k] += (float)u0[k]; a[k + 8] += (float)u1[k]; }
    }
    float inv = 1.f / fmaxf((float)nc, 1.f);
    f16x8 o0, o1;
#pragma unroll
    for (int k = 0; k < 8; ++k){ o0[k] = (f16)(a[k] * inv); o1[k] = (f16)(a[k + 8] * inv); }
    *(f16x8*)&AT[r][c0]     = o0;
    *(f16x8*)&AT[r][c0 + 8] = o1;
  }
  __syncthreads();

  int wave = t >> 6, l = t & 63;
  int lrow = l & 15;
  int lk = (l >> 4) * 8;
  int rt = wave >> 1, nh = wave & 1;
  int rowW = rowBase + rt * 16;

  f32x4 acc[4];
#pragma unroll
  for (int q = 0; q < 4; ++q) acc[q] = (f32x4){0.f, 0.f, 0.f, 0.f};

#pragma unroll
  for (int kc = 0; kc < 4; ++kc){
    int kb = kc * 32 + lk;
    f16x8 a0 = *(const f16x8*)&AT[rt * 16 + lrow][kb];
#pragma unroll
    for (int q = 0; q < 4; ++q){
      int nt = nh * 4 + q;
      f16x8 bw = *(const f16x8*)&WaT[(nt * 16 + lrow) * 128 + kb];
      acc[q] = __builtin_amdgcn_mfma_f32_16x16x32_f16(a0, bw, acc[q], 0, 0, 0);
    }
    if (DUAL){
      f16x8 c0v = *(const f16x8*)&Bm[(rowW + lrow) * 128 + kb];
#pragma unroll
      for (int q = 0; q < 4; ++q){
        int nt = nh * 4 + q;
        f16x8 bw = *(const f16x8*)&WbT[(nt * 16 + lrow) * 128 + kb];
        acc[q] = __builtin_amdgcn_mfma_f32_16x16x32_f16(c0v, bw, acc[q], 0, 0, 0);
      }
    }
  }

  int col16 = l & 15;
  int rgrp = (l >> 4) * 4;
#pragma unroll
  for (int r = 0; r < 4; ++r){
    int row = rowW + rgrp + r;
    float v[4];
#pragma unroll
    for (int q = 0; q < 4; ++q) v[q] = acc[q][r] + bi[(nh * 4 + q) * 16 + col16];
    if (ACT == 1){
#pragma unroll
      for (int q = 0; q < 4; ++q) v[q] = mishf(v[q]);
    }
    if (FUSEADD){
#pragma unroll
      for (int q = 0; q < 4; ++q)
        v[q] += (float)ADD[row * 128 + (nh * 4 + q) * 16 + col16];
    }
#pragma unroll
    for (int q = 0; q < 4; ++q)
      O[row * 128 + (nh * 4 + q) * 16 + col16] = (f16)v[q];
  }
}

// ---------------------------------------------------------------- fused MLP: t = H@W1+b1 (LDS), s = softmax(t@W2+b2)
__global__ __launch_bounds__(128) void mlp_kernel(
    const f16* __restrict__ H0, const f16* __restrict__ H1,
    const f16* __restrict__ W1T, const f16* __restrict__ W2T,
    const float* __restrict__ b1, const float* __restrict__ b2,
    f16* __restrict__ O0, f16* __restrict__ O1,
    unsigned char* __restrict__ S80, unsigned char* __restrict__ S81){
  int g = blockIdx.y;
  const f16* A = g ? H1 : H0;
  f16* O = g ? O1 : O0;
  unsigned char* S8 = g ? S81 : S80;

  __shared__ f16 T[32][136];
  int t = threadIdx.x;
  int wave = t >> 6, l = t & 63;
  int lrow = l & 15;
  int lk = (l >> 4) * 8;
  int rowBase = blockIdx.x * 32 + wave * 16;
  int col16 = l & 15;
  int rgrp = (l >> 4) * 4;

  f32x4 acc[8];
#pragma unroll
  for (int nt = 0; nt < 8; ++nt) acc[nt] = (f32x4){0.f, 0.f, 0.f, 0.f};
#pragma unroll
  for (int kc = 0; kc < 4; ++kc){
    int kb = kc * 32 + lk;
    f16x8 a0 = *(const f16x8*)&A[(rowBase + lrow) * 128 + kb];
#pragma unroll
    for (int nt = 0; nt < 8; ++nt){
      f16x8 bw = *(const f16x8*)&W1T[(nt * 16 + lrow) * 128 + kb];
      acc[nt] = __builtin_amdgcn_mfma_f32_16x16x32_f16(a0, bw, acc[nt], 0, 0, 0);
    }
  }
#pragma unroll
  for (int r = 0; r < 4; ++r)
#pragma unroll
    for (int nt = 0; nt < 8; ++nt)
      T[wave * 16 + rgrp + r][nt * 16 + col16] = (f16)(acc[nt][r] + b1[nt * 16 + col16]);
  __syncthreads();

  f32x4 acc2[8];
#pragma unroll
  for (int nt = 0; nt < 8; ++nt) acc2[nt] = (f32x4){0.f, 0.f, 0.f, 0.f};
#pragma unroll
  for (int kc = 0; kc < 4; ++kc){
    int kb = kc * 32 + lk;
    f16x8 a0 = *(const f16x8*)&T[wave * 16 + lrow][kb];
#pragma unroll
    for (int nt = 0; nt < 8; ++nt){
      f16x8 bw = *(const f16x8*)&W2T[(nt * 16 + lrow) * 128 + kb];
      acc2[nt] = __builtin_amdgcn_mfma_f32_16x16x32_f16(a0, bw, acc2[nt], 0, 0, 0);
    }
  }

  float bv[8];
#pragma unroll
  for (int nt = 0; nt < 8; ++nt) bv[nt] = b2[nt * 16 + col16];
#pragma unroll
  for (int r = 0; r < 4; ++r){
    int row = rowBase + rgrp + r;
    float v[8];
#pragma unroll
    for (int nt = 0; nt < 8; ++nt) v[nt] = acc2[nt][r] + bv[nt];
    float m = v[0];
#pragma unroll
    for (int nt = 1; nt < 8; ++nt) m = fmaxf(m, v[nt]);
    for (int msk = 1; msk < 16; msk <<= 1) m = fmaxf(m, __shfl_xor(m, msk));
    float sum = 0.f;
#pragma unroll
    for (int nt = 0; nt < 8; ++nt){ v[nt] = __expf(v[nt] - m); sum += v[nt]; }
    for (int msk = 1; msk < 16; msk <<= 1) sum += __shfl_xor(sum, msk);
    float inv = 1.f / sum;
#pragma unroll
    for (int nt = 0; nt < 8; ++nt) v[nt] *= inv;
#pragma unroll
    for (int nt = 0; nt < 8; ++nt){
      O[row * 128 + nt * 16 + col16] = (f16)v[nt];
      S8[row * 128 + nt * 16 + col16] = enc_fp8(v[nt] * 64.f);
    }
  }
}

// ---------------------------------------------------------------- transpose [8192][128]->[128][8192] (+colsum for z=0)
__global__ __launch_bounds__(256) void transpose_kernel(
    const f16* __restrict__ in0A, const f16* __restrict__ in1A,   // z=0 src (S)
    const f16* __restrict__ in0B, const f16* __restrict__ in1B,   // z=1 src (Hf)
    f16* __restrict__ o0A, f16* __restrict__ o1A,
    f16* __restrict__ o0B, f16* __restrict__ o1B,
    float* col0, float* col1){
  int g = blockIdx.y, z = blockIdx.z;
  const f16* in = z ? (g ? in1B : in0B) : (g ? in1A : in0A);
  f16* outp     = z ? (g ? o1B  : o0B)  : (g ? o1A  : o0A);
  __shared__ f16 T[32][136];
  int t = threadIdx.x;
  int i0 = blockIdx.x * 32;
#pragma unroll
  for (int j = 0; j < 2; ++j){
    int idx = t + j * 256;
    int row = idx >> 4, c8 = (idx & 15) * 8;
    f16x8 v = *(const f16x8*)&in[(i0 + row) * 128 + c8];
#pragma unroll
    for (int q = 0; q < 8; ++q) T[row][c8 + q] = v[q];
  }
  __syncthreads();
  int k = t >> 1, seg = (t & 1) * 16;
  f16x8 oA, oB;
#pragma unroll
  for (int q = 0; q < 8; ++q){ oA[q] = T[seg + q][k]; oB[q] = T[seg + 8 + q][k]; }
  *(f16x8*)&outp[(size_t)k * NN + i0 + seg]     = oA;
  *(f16x8*)&outp[(size_t)k * NN + i0 + seg + 8] = oB;

  if (z == 0){
    float* col = g ? col1 : col0;
    int kk = t & 127, half = t >> 7;
    float cs = 0.f;
#pragma unroll
    for (int i = 0; i < 16; ++i)
      cs += (float)T[half * 16 + i][kk];
    atomicAdd(&col[kk], cs);
  }
}

// ---------------------------------------------------------------- merged pool (MFMA split-K) + trace (fp8) + ca (reg+padded LDS)
// grid (544, 2): bx<32 -> pool; bx>=32 -> trace (16 nodes/block, full buckets)
#define PK_NSPLIT 16
__global__ __launch_bounds__(256) void pooltrace_kernel(
    const f16* __restrict__ ST0, const f16* __restrict__ ST1,
    const f16* __restrict__ HT0, const f16* __restrict__ HT1,
    float* __restrict__ PART,
    const int* __restrict__ cntA, const int* __restrict__ cntB,
    const int* __restrict__ bkA, const int* __restrict__ bkB,
    const f16* __restrict__ SA, const f16* __restrict__ SBp,
    const unsigned char* __restrict__ S8A, const unsigned char* __restrict__ S8B,
    float* tr0, float* tr1, float* ca0, float* ca1){
  int g = blockIdx.y;
  int bx = blockIdx.x;
  int t = threadIdx.x;
  if (bx < 32){
    int z = bx >> 4, split = bx & 15;
    const f16* A = g ? ST1 : ST0;
    const f16* B = z ? A : (g ? HT1 : HT0);
    float* OUT = PART + ((size_t)(z * 2 + g) * PK_NSPLIT + split) * 16384;

    int wave = t >> 6, l = t & 63;
    int lrow = l & 15;
    int lk = (l >> 4) * 8;
    int krow = wave * 32;
    int i0 = split * (NN / PK_NSPLIT);

    f32x4 acc[2][8];
#pragma unroll
    for (int rt = 0; rt < 2; ++rt)
#pragma unroll
      for (int nt = 0; nt < 8; ++nt)
        acc[rt][nt] = (f32x4){0.f, 0.f, 0.f, 0.f};

#pragma unroll 2
    for (int c = 0; c < NN / PK_NSPLIT; c += 32){
      int ib = i0 + c + lk;
      f16x8 a0 = *(const f16x8*)&A[(size_t)(krow + lrow) * NN + ib];
      f16x8 a1 = *(const f16x8*)&A[(size_t)(krow + 16 + lrow) * NN + ib];
#pragma unroll
      for (int nt = 0; nt < 8; ++nt){
        f16x8 bf = *(const f16x8*)&B[(size_t)(nt * 16 + lrow) * NN + ib];
        acc[0][nt] = __builtin_amdgcn_mfma_f32_16x16x32_f16(a0, bf, acc[0][nt], 0, 0, 0);
        acc[1][nt] = __builtin_amdgcn_mfma_f32_16x16x32_f16(a1, bf, acc[1][nt], 0, 0, 0);
      }
    }

    int col = l & 15;
    int rbase = (l >> 4) * 4;
#pragma unroll
    for (int rt = 0; rt < 2; ++rt)
#pragma unroll
      for (int nt = 0; nt < 8; ++nt)
#pragma unroll
        for (int r = 0; r < 4; ++r)
          OUT[(krow + rt * 16 + rbase + r) * 128 + nt * 16 + col] = acc[rt][nt][r];
  } else {
    const int* cnt = g ? cntB : cntA;
    const int* bk  = g ? bkB  : bkA;
    const f16* S = g ? SBp : SA;
    const unsigned char* S8 = g ? S8B : S8A;
    float* tr = g ? tr1 : tr0;
    float* ca = g ? ca1 : ca0;
    int grp = t >> 4, lane = t & 15;       // 16 nodes/block, 16 lanes x 8 elems
    int node = (bx - 32) * 16 + grp;
    int nc = cnt[node];
    const int* lst = bk + node * BCAP;
    f16x8 w = *(const f16x8*)&S[node * DD + lane * 8];   // exact fp16 dst row
    float o[8], cak[8];
#pragma unroll
    for (int k = 0; k < 8; ++k){ o[k] = (float)w[k]; cak[k] = 0.f; }
    float acc = 0.f;
    int j = 0;
    for (; j + 4 <= nc; j += 4){
      int s0 = lst[j], s1 = lst[j + 1], s2 = lst[j + 2], s3 = lst[j + 3];
      uint2 q0 = *(const uint2*)&S8[s0 * DD + lane * 8];
      uint2 q1 = *(const uint2*)&S8[s1 * DD + lane * 8];
      uint2 q2 = *(const uint2*)&S8[s2 * DD + lane * 8];
      uint2 q3 = *(const uint2*)&S8[s3 * DD + lane * 8];
#pragma unroll
      for (int k = 0; k < 4; ++k){
        float lo = (dec_fp8((q0.x >> (8*k)) & 0xFF) + dec_fp8((q1.x >> (8*k)) & 0xFF))
                 + (dec_fp8((q2.x >> (8*k)) & 0xFF) + dec_fp8((q3.x >> (8*k)) & 0xFF));
        float hi = (dec_fp8((q0.y >> (8*k)) & 0xFF) + dec_fp8((q1.y >> (8*k)) & 0xFF))
                 + (dec_fp8((q2.y >> (8*k)) & 0xFF) + dec_fp8((q3.y >> (8*k)) & 0xFF));
        acc += o[k] * lo + o[k + 4] * hi;
        cak[k] += lo; cak[k + 4] += hi;
      }
    }
    for (; j < nc; ++j){
      int s = lst[j];
      uint2 q = *(const uint2*)&S8[s * DD + lane * 8];
#pragma unroll
      for (int k = 0; k < 4; ++k){
        float lo = dec_fp8((q.x >> (8*k)) & 0xFF);
        float hi = dec_fp8((q.y >> (8*k)) & 0xFF);
        acc += o[k] * lo + o[k + 4] * hi;
        cak[k] += lo; cak[k + 4] += hi;
      }
    }
    for (int m = 1; m < 16; m <<= 1) acc += __shfl_xor(acc, m);
    __shared__ float part[16];
    __shared__ float pca[128][17];   // transposed + padded: 4-way max write conflict
    if (lane == 0) part[grp] = acc;
#pragma unroll
    for (int k = 0; k < 8; ++k) pca[lane * 8 + k][grp] = cak[k];
    __syncthreads();
    if (t == 0){
      float s = 0.f;
#pragma unroll
      for (int i = 0; i < 16; ++i) s += part[i];
      atomicAdd(tr, s * 0.015625f);   // /64 (fp8 stored S*64)
    }
    if (t < 128){
      float s = 0.f;
#pragma unroll
      for (int i = 0; i < 16; ++i) s += pca[t][i];
      atomicAdd(&ca[t], s * 0.015625f);
    }
  }
}

// ---------------------------------------------------------------- reduce partials; z=0 -> selu->out, z=1 -> F2/trss scalars
__global__ __launch_bounds__(256) void reduce_kernel(
    const float* __restrict__ PART,
    float* __restrict__ out, float* F2acc, float* trssacc){
  int g = blockIdx.y, z = blockIdx.z;
  int t = threadIdx.x;
  int idx = blockIdx.x * 256 + t;
  const float* base = PART + (size_t)(z * 2 + g) * PK_NSPLIT * 16384 + idx;
  float s = 0.f;
#pragma unroll
  for (int sp = 0; sp < PK_NSPLIT; ++sp) s += base[sp * 16384];
  if (z == 0){
    const float scale = 1.0507009873554805f, alpha = 1.6732632423543772f;
    float r = (s > 0.f) ? scale * s : scale * alpha * expm1f(s);
    out[g * 16384 + idx] = r;
  } else {
    float f2p = s * s;
    float trp = (idx % 129 == 0) ? s : 0.f;
    __shared__ float r1[256], r2[256];
    r1[t] = f2p; r2[t] = trp; __syncthreads();
    for (int o = 128; o > 0; o >>= 1){
      if (t < o){ r1[t] += r1[t + o]; r2[t] += r2[t + o]; }
      __syncthreads();
    }
    if (t == 0){
      atomicAdd(&F2acc[g], r1[0]);
      atomicAdd(&trssacc[g], r2[0]);
    }
  }
}

// ---------------------------------------------------------------- finalize: both graphs, direct store
__global__ __launch_bounds__(128) void finalize_kernel(
    const float* col0, const float* col1, const float* ca0, const float* ca1,
    const float* tr0, const float* tr1, const float* F2acc, const float* trssacc,
    float* loss_out){
  __shared__ float r1[128], r2[128];
  __shared__ float total_s;
  int t = threadIdx.x;
  if (t == 0) total_s = 0.f;
  for (int g = 0; g < 2; ++g){
    const float* col = g ? col1 : col0;
    const float* ca  = g ? ca1  : ca0;
    const float* tr  = g ? tr1  : tr0;
    __syncthreads();
    r1[t] = ca[t] * ca[t];
    r2[t] = col[t] * col[t];
    __syncthreads();
    for (int o = 64; o > 0; o >>= 1){
      if (t < o){ r1[t] += r1[t + o]; r2[t] += r2[t + o]; }
      __syncthreads();
    }
    if (t == 0){
      float ca2 = r1[0], cs2 = r2[0];
      float F = sqrtf(F2acc[g]);
      float ortho = sqrtf(fmaxf(2.f - 2.f * trssacc[g] / (F * sqrtf((float)KK)), 0.f));
      float m2 = (float)EE;               // 2m
      float spectral = -(tr[0] - ca2 / m2) / m2;
      float cluster = sqrtf(cs2) / (float)NN * sqrtf((float)KK) - 1.f;
      total_s += spectral + ortho + cluster;
    }
  }
  __syncthreads();
  if (t == 0) loss_out[0] = total_s;
}

// ---------------------------------------------------------------- launch
extern "C" void kernel_launch(void* const* d_in, const int* in_sizes, int n_in,
                              void* d_out, int out_size, void* d_ws, size_t ws_size,
                              hipStream_t stream){
  const float* x1 = (const float*)d_in[0];
  const float* x2 = (const float*)d_in[1];
  const int*   e1 = (const int*)d_in[2];
  const int*   e2 = (const int*)d_in[3];
  const float* c1_Wl = (const float*)d_in[4];
  const float* c1_bl = (const float*)d_in[5];
  const float* c1_Wr = (const float*)d_in[6];
  const float* c2_Wl = (const float*)d_in[7];
  const float* c2_bl = (const float*)d_in[8];
  const float* c2_Wr = (const float*)d_in[9];
  const float* co_Wl = (const float*)d_in[10];
  const float* co_bl = (const float*)d_in[11];
  const float* co_Wr = (const float*)d_in[12];
  const float* c3_Wl = (const float*)d_in[13];
  const float* c3_bl = (const float*)d_in[14];
  const float* c3_Wr = (const float*)d_in[15];
  const float* c4_Wl = (const float*)d_in[16];
  const float* c4_bl = (const float*)d_in[17];
  const float* c4_Wr = (const float*)d_in[18];
  const float* m_W1 = (const float*)d_in[19];
  const float* m_b1 = (const float*)d_in[20];
  const float* m_W2 = (const float*)d_in[21];
  const float* m_b2 = (const float*)d_in[22];
  float* out = (float*)d_out;

  char* w = (char*)d_ws;
  auto alloc = [&](size_t bytes) -> char* {
    char* p = w;
    w += (bytes + 255) / 256 * 256;
    return p;
  };
  // zero region: counts + small accumulators (contiguous)
  int* cnt0 = (int*)alloc(NN * 4);
  int* cnt1 = (int*)alloc(NN * 4);
  float* col0 = (float*)alloc(128 * 4);
  float* ca0  = (float*)alloc(128 * 4);
  float* tr0  = (float*)alloc(256);
  float* col1 = (float*)alloc(128 * 4);
  float* ca1  = (float*)alloc(128 * 4);
  float* tr1  = (float*)alloc(256);
  float* F2acc   = (float*)alloc(2 * 4);
  float* trssacc = (float*)alloc(2 * 4);
  size_t zero_len = (size_t)(w - (char*)cnt0);
  // buckets (only slots < cnt read; no zeroing)
  int* bk0 = (int*)alloc((size_t)NN * BCAP * 4);
  int* bk1 = (int*)alloc((size_t)NN * BCAP * 4);
  // split-K partials: [z][g][split][16384]
  float* PART = (float*)alloc((size_t)4 * PK_NSPLIT * 16384 * 4);
  // transposed fp16 weights (12 x 128x128)
  f16* WT = (f16*)alloc(12 * 16384 * sizeof(f16));
  // fp8 S copies for trace
  unsigned char* S8_0 = (unsigned char*)alloc((size_t)NN * DD);
  unsigned char* S8_1 = (unsigned char*)alloc((size_t)NN * DD);
  // fp16 feature buffers, 2 MB each
  f16* F1_0 = (f16*)alloc((size_t)NN * DD * 2);
  f16* F3_0 = (f16*)alloc((size_t)NN * DD * 2);
  f16* F4_0 = (f16*)alloc((size_t)NN * DD * 2);
  f16* F5_0 = (f16*)alloc((size_t)NN * DD * 2);
  f16* F1_1 = (f16*)alloc((size_t)NN * DD * 2);
  f16* F3_1 = (f16*)alloc((size_t)NN * DD * 2);
  f16* F4_1 = (f16*)alloc((size_t)NN * DD * 2);
  f16* F5_1 = (f16*)alloc((size_t)NN * DD * 2);

  hipMemsetAsync(cnt0, 0, zero_len, stream);

  // fused prep: cast x->fp16 + single-pass bucket CSR + weight transpose
  prep_kernel<<<dim3(774, 2), 256, 0, stream>>>(
      x1, x2, F1_0, F1_1, e1, e2, cnt0, cnt1, bk0, bk1,
      c1_Wl, c1_Wr, c2_Wl, c2_Wr, co_Wl, co_Wr,
      c3_Wl, c3_Wr, c4_Wl, c4_Wr, m_W1, m_W2, WT);

  f16* W_c1l = WT;            f16* W_c1r = WT + 16384;
  f16* W_c2l = WT + 2*16384;  f16* W_c2r = WT + 3*16384;
  f16* W_col = WT + 4*16384;  f16* W_cor = WT + 5*16384;
  f16* W_c3l = WT + 6*16384;  f16* W_c3r = WT + 7*16384;
  f16* W_c4l = WT + 8*16384;  f16* W_c4r = WT + 9*16384;
  f16* W_m1  = WT + 10*16384; f16* W_m2  = WT + 11*16384;

  // sage1: h = mish(mean(x)@Wl + x@Wr + bl) -> F3   (fused agg+gemm)
  aggemm<1, 1, 0><<<dim3(256, 2), 256, 0, stream>>>(cnt0, cnt1, bk0, bk1,
      F1_0, F1_1, F1_0, F1_1, W_c1l, W_c2l, W_c1r, W_c2r, c1_bl, c2_bl,
      nullptr, nullptr, F3_0, F3_1);

  // sage2 (shared co weights) + residual: z = h + mish(sage(h)) -> F1
  aggemm<1, 1, 1><<<dim3(256, 2), 256, 0, stream>>>(cnt0, cnt1, bk0, bk1,
      F3_0, F3_1, F3_0, F3_1, W_col, W_col, W_cor, W_cor, co_bl, co_bl,
      F3_0, F3_1, F1_0, F1_1);

  // sage3: h_final = mish(sage(z)) -> F4
  aggemm<1, 1, 0><<<dim3(256, 2), 256, 0, stream>>>(cnt0, cnt1, bk0, bk1,
      F1_0, F1_1, F1_0, F1_1, W_c3l, W_c4l, W_c3r, W_c4r, c3_bl, c4_bl,
      nullptr, nullptr, F4_0, F4_1);

  // dmon MLP fused: s = softmax((h@W1+b1)@W2+b2) -> F5 (+ fp8 copy -> S8)
  mlp_kernel<<<dim3(256, 2), 128, 0, stream>>>(F4_0, F4_1, W_m1, W_m2,
      m_b1, m_b2, F5_0, F5_1, S8_0, S8_1);

  // transpose S -> ST (F1), Hf -> HT (F3); colsum fused on z=0
  transpose_kernel<<<dim3(256, 2, 2), 256, 0, stream>>>(
      F5_0, F5_1, F4_0, F4_1, F1_0, F1_1, F3_0, F3_1, col0, col1);

  // merged: pooled/ss split-K MFMA + trace gather (fp8) + ca
  pooltrace_kernel<<<dim3(544, 2), 256, 0, stream>>>(
      F1_0, F1_1, F3_0, F3_1, PART,
      cnt0, cnt1, bk0, bk1, F5_0, F5_1, S8_0, S8_1, tr0, tr1, ca0, ca1);
  reduce_kernel<<<dim3(64, 2, 2), 256, 0, stream>>>(PART, out, F2acc, trssacc);

  finalize_kernel<<<1, 128, 0, stream>>>(col0, col1, ca0, ca1, tr0, tr1,
      F2acc, trssacc, out + 32768);
}